// Round 5
// baseline (118.360 us; speedup 1.0000x reference)
//
#include <hip/hip_runtime.h>
#include <hip/hip_bf16.h>

// MultiScaleRoIAlign for FPN — LDS window staging.
//   feats NCHW f32: stride {4,8,16,32} -> (2,256,256,256)/(2,256,128,128)/(2,256,64,64)/(2,256,32,32)
//   boxes (2,256,4) xyxy, IMG=1024; out (512,256,7,7) f32
// Level: lvl = clip(floor(4 + log2(sqrt(area)/224 + 1e-8)), 2, 5) - 2
// ALIGNED=False, roi w/h >= 1, mask (s > -1 && s < H) else 0.
//
// Block = (roi, 8 channels). The 49 bins' bilinear taps of one channel cover a
// contiguous window [y0(0)..y0(6)+1] x [x0(0)..x0(6)+1] (ys/xs monotone in
// py/px). Level selection bounds the window area: cell-area < 784 =>
// window elems <= ~820 < 1024. Stage 8 windows into LDS with contiguous
// cooperative loads (each line fetched once, ~8 independent loads in flight
// per thread), compute 392 outputs from LDS, store coalesced.

#define C_DIM 256
#define OUTB 7
#define NBINS 49
#define PER_ROI 12544        // 256*49
#define NROI 512
#define CPB 8                // channels per block
#define BLK_PER_ROI 32       // 256/8
#define TPB 256
#define WIN_MAX 1024         // per-channel window floats (bounded ~820)
#define NXCD 8
#define ROI_PER_XCD (NROI / NXCD)   // 64

__global__ __launch_bounds__(TPB) void msroi_lds_kernel(
    const float* __restrict__ f0, const float* __restrict__ f1,
    const float* __restrict__ f2, const float* __restrict__ f3,
    const float* __restrict__ boxes, float* __restrict__ out) {
  // 16384 blocks = 8 XCDs x 2048 (= 64 rois x 32 channel-groups). Consecutive
  // blockIdx round-robin XCDs; give XCD k rois [64k, 64k+64) so a roi's
  // window set lives in one L2.
  const int wg   = blockIdx.x;
  const int xcd  = wg & (NXCD - 1);
  const int slot = wg >> 3;             // 0..2047
  const int rr   = slot >> 5;           // 0..63
  const int cb   = (slot & 31) * CPB;   // channel base 0,8,..,248
  const int r    = xcd * ROI_PER_XCD + rr;
  const int n    = r >> 8;
  const int tid  = threadIdx.x;

  const float4 box = ((const float4*)boxes)[r];

  // ---- level selection (exact reference arithmetic; uniform) ----
  float bwp = fmaxf(box.z - box.x, 0.0f);
  float bhp = fmaxf(box.w - box.y, 0.0f);
  float lv = floorf(4.0f + log2f(sqrtf(bwp * bhp) / 224.0f + 1e-8f));
  const int lvl = (int)(fminf(fmaxf(lv, 2.0f), 5.0f)) - 2;  // 0..3
  const float* __restrict__ feat;
  switch (lvl) {
    case 0:  feat = f0; break;
    case 1:  feat = f1; break;
    case 2:  feat = f2; break;
    default: feat = f3; break;
  }
  const int sh = 8 - lvl;          // W = H = 1<<sh
  const int H = 1 << sh, W = H;
  const int hw_sh = 2 * sh;
  const float scale = 1.0f / (float)(4 << lvl);

  __shared__ float win[CPB][WIN_MAX];          // 32 KB
  __shared__ int   g_y0[NBINS], g_x0[NBINS];
  __shared__ float g_ly[NBINS], g_lx[NBINS], g_vm[NBINS];

  // ---- phase 1: per-bin geometry (exactly reference-rounded) ----
  if (tid < NBINS) {
    const int py = tid / OUTB, px = tid - py * OUTB;
    const float x1 = box.x * scale, y1 = box.y * scale;
    const float x2 = box.z * scale, y2 = box.w * scale;
    const float rw = fmaxf(x2 - x1, 1.0f), rh = fmaxf(y2 - y1, 1.0f);
    const float binw = rw / (float)OUTB, binh = rh / (float)OUTB;
    // no fma contraction: mask comparisons must match numpy bit-for-bit
    const float ysf = __fadd_rn(y1, __fmul_rn((float)py + 0.5f, binh));
    const float xsf = __fadd_rn(x1, __fmul_rn((float)px + 0.5f, binw));
    const bool vy = (ysf > -1.0f) && (ysf < (float)H);
    const bool vx = (xsf > -1.0f) && (xsf < (float)W);
    float y = fminf(fmaxf(ysf, 0.0f), (float)(H - 1));
    float x = fminf(fmaxf(xsf, 0.0f), (float)(W - 1));
    const int y0 = min((int)floorf(y), H - 2);
    const int x0 = min((int)floorf(x), W - 2);
    g_y0[tid] = y0;  g_x0[tid] = x0;
    g_ly[tid] = y - (float)y0;  g_lx[tid] = x - (float)x0;
    g_vm[tid] = (vy && vx) ? 1.0f : 0.0f;
  }
  __syncthreads();

  // ---- window bounds (monotone ys/xs => bins 0, 6, 42 give extremes) ----
  const int wrow0 = g_y0[0];
  const int wcol0 = g_x0[0];
  const unsigned wrows = (unsigned)(g_y0[42] + 2 - wrow0);  // <= H
  const unsigned wcols = (unsigned)(g_x0[6] + 2 - wcol0);   // >= 2
  unsigned total = wrows * wcols;
  if (total > WIN_MAX) total = WIN_MAX;  // provably unreachable; LDS guard
  // exact magic division by wcols (k*e < 2^32 since k<1024, e<=wcols<=130)
  const unsigned magic = (unsigned)(0x100000000ULL / wcols + 1);

  // ---- phase 2: cooperative contiguous staging, one fetch per line ----
  const float* __restrict__ fb =
      feat + (((size_t)(n * C_DIM + cb)) << hw_sh) + ((size_t)wrow0 << sh) + wcol0;
#pragma unroll
  for (int ch = 0; ch < CPB; ch++) {
    const float* __restrict__ fc = fb + ((size_t)ch << hw_sh);
    for (unsigned k = tid; k < total; k += TPB) {
      const unsigned row = __umulhi(k, magic);
      const unsigned col = k - row * wcols;
      win[ch][k] = fc[(row << sh) + col];
    }
  }
  __syncthreads();

  // ---- phase 3: 392 outputs from LDS, coalesced store ----
  float* __restrict__ o = out + (size_t)r * PER_ROI + (size_t)cb * NBINS;
  for (int k2 = tid; k2 < CPB * NBINS; k2 += TPB) {
    const int ch = k2 / NBINS;             // compile-time magic (49)
    const int bin = k2 - ch * NBINS;
    const int tap = (g_y0[bin] - wrow0) * (int)wcols + (g_x0[bin] - wcol0);
    const float ly = g_ly[bin], lx = g_lx[bin], vm = g_vm[bin];
    const float v00 = win[ch][tap];
    const float v01 = win[ch][tap + 1];
    const float v10 = win[ch][tap + wcols];
    const float v11 = win[ch][tap + wcols + 1];
    const float wy0 = 1.0f - ly, wx0 = 1.0f - lx;
    o[k2] = vm * (wy0 * (wx0 * v00 + lx * v01) + ly * (wx0 * v10 + lx * v11));
  }
}

extern "C" void kernel_launch(void* const* d_in, const int* in_sizes, int n_in,
                              void* d_out, int out_size, void* d_ws, size_t ws_size,
                              hipStream_t stream) {
  const float* f0 = (const float*)d_in[0];
  const float* f1 = (const float*)d_in[1];
  const float* f2 = (const float*)d_in[2];
  const float* f3 = (const float*)d_in[3];
  const float* boxes = (const float*)d_in[4];
  float* out = (float*)d_out;

  dim3 grid(NROI * BLK_PER_ROI);  // 16384
  dim3 block(TPB);
  msroi_lds_kernel<<<grid, block, 0, stream>>>(f0, f1, f2, f3, boxes, out);
}

// Round 6
// 26.675 us; speedup vs baseline: 4.4372x; 4.4372x over previous
//
#include <hip/hip_runtime.h>
#include <hip/hip_bf16.h>

// MultiScaleRoIAlign for FPN, direct gather (NCHW f32), channel-partitioned
// XCD scheduling.
//   feats: stride {4,8,16,32} -> (2,256,256,256)/(2,256,128,128)/(2,256,64,64)/(2,256,32,32)
//   boxes: (2,256,4) xyxy, IMG=1024; out: (512,256,7,7) f32
// Level: lvl = clip(floor(4 + log2(sqrt(area)/224 + 1e-8)), 2, 5) - 2
// ALIGNED=False, roi w/h >= 1, mask (s > -1 && s < H) else 0.
//
// Scheduling: channels are DISJOINT data across blocks. Give XCD x the 4
// channel-groups [4x,4x+4) (8 ch each) and sweep all 512 rois roi-major:
// every feature-plane line is fetched by exactly ONE XCD's L2, and the
// per-XCD touched union (~5-6 MB) nearly fits the 4 MB L2 -> cross-roi
// window overlap becomes L2 hits instead of refetches (R5 measured 202 MB
// miss traffic with per-roi scheduling; union of touched lines is ~45 MB).
// Output stores are nontemporal (streaming, no reuse) to keep L2 for windows.

#define C_DIM 256
#define OUTB 7
#define NBINS 49
#define PER_ROI 12544        // 256*49
#define NROI 512
#define CPB 8                // channels per block
#define OUTS_PB (CPB * NBINS)   // 392 outputs per block
#define TPB 256
#define NXCD 8

__global__ __launch_bounds__(TPB) void msroi_xcd_kernel(
    const float* __restrict__ f0, const float* __restrict__ f1,
    const float* __restrict__ f2, const float* __restrict__ f3,
    const float* __restrict__ boxes, float* __restrict__ out) {
  // 16384 blocks. blockIdx round-robins XCDs (d&7). XCD x gets slots s=d>>3:
  // roi = s>>2 (roi-major sweep), local cgroup = s&3, cgroup = x*4 + (s&3).
  const int d      = blockIdx.x;
  const int xcd    = d & (NXCD - 1);
  const int s      = d >> 3;            // 0..2047
  const int r      = s >> 2;            // 0..511
  const int cgroup = xcd * 4 + (s & 3); // 0..31
  const int cb     = cgroup * CPB;      // channel base
  const int n      = r >> 8;            // 256 rois per image
  const int tid    = threadIdx.x;

  const float4 box = ((const float4*)boxes)[r];

  // ---- level selection (exact reference arithmetic; block-uniform) ----
  float bwp = fmaxf(box.z - box.x, 0.0f);
  float bhp = fmaxf(box.w - box.y, 0.0f);
  float lv = floorf(4.0f + log2f(sqrtf(bwp * bhp) / 224.0f + 1e-8f));
  const int lvl = (int)(fminf(fmaxf(lv, 2.0f), 5.0f)) - 2;  // 0..3

  const float* __restrict__ feat;
  switch (lvl) {
    case 0:  feat = f0; break;
    case 1:  feat = f1; break;
    case 2:  feat = f2; break;
    default: feat = f3; break;
  }
  const int sh = 8 - lvl;          // W = H = 1 << sh
  const int H = 1 << sh, W = H;
  const int hw_sh = 2 * sh;
  const float scale = 1.0f / (float)(4 << lvl);

  // ---- ROI geometry (block-uniform part) ----
  const float x1 = box.x * scale, y1 = box.y * scale;
  const float x2 = box.z * scale, y2 = box.w * scale;
  const float roi_w = fmaxf(x2 - x1, 1.0f);
  const float roi_h = fmaxf(y2 - y1, 1.0f);
  const float bin_w = roi_w / (float)OUTB;
  const float bin_h = roi_h / (float)OUTB;

  float* __restrict__ obase = out + (size_t)r * PER_ROI + (size_t)cb * NBINS;

  // Each thread: outputs le = tid and le = tid + 256 (if < 392).
#pragma unroll
  for (int half = 0; half < 2; half++) {
    const int le = tid + half * TPB;
    if (le >= OUTS_PB) break;
    const int cl  = le / NBINS;          // 0..7 (magic mul, const divisor)
    const int bin = le - cl * NBINS;
    const int py  = bin / OUTB;
    const int px  = bin - py * OUTB;

    // Boundary-sensitive: no fma contraction (mask must match numpy).
    const float ysf = __fadd_rn(y1, __fmul_rn((float)py + 0.5f, bin_h));
    const float xsf = __fadd_rn(x1, __fmul_rn((float)px + 0.5f, bin_w));
    const bool vy = (ysf > -1.0f) && (ysf < (float)H);
    const bool vx = (xsf > -1.0f) && (xsf < (float)W);
    const float vm = (vy && vx) ? 1.0f : 0.0f;

    float y = fminf(fmaxf(ysf, 0.0f), (float)(H - 1));
    float x = fminf(fmaxf(xsf, 0.0f), (float)(W - 1));
    const int y0 = min((int)floorf(y), H - 2);
    const int x0 = min((int)floorf(x), W - 2);
    const float ly = y - (float)y0;
    const float lx = x - (float)x0;
    const float wy0 = 1.0f - ly, wx0 = 1.0f - lx;

    const float* __restrict__ p =
        feat + (((size_t)(n * C_DIM + cb + cl)) << hw_sh) +
        ((size_t)y0 << sh) + (size_t)x0;
    const float2 v0 = *reinterpret_cast<const float2*>(p);
    const float2 v1 = *reinterpret_cast<const float2*>(p + W);

    const float val =
        vm * (wy0 * (wx0 * v0.x + lx * v0.y) + ly * (wx0 * v1.x + lx * v1.y));
    // Streaming store: keep out of L2 so window lines stay resident.
    __builtin_nontemporal_store(val, obase + le);
  }
}

extern "C" void kernel_launch(void* const* d_in, const int* in_sizes, int n_in,
                              void* d_out, int out_size, void* d_ws, size_t ws_size,
                              hipStream_t stream) {
  const float* f0 = (const float*)d_in[0];
  const float* f1 = (const float*)d_in[1];
  const float* f2 = (const float*)d_in[2];
  const float* f3 = (const float*)d_in[3];
  const float* boxes = (const float*)d_in[4];
  float* out = (float*)d_out;

  dim3 grid(NROI * (C_DIM / CPB));  // 16384
  dim3 block(TPB);
  msroi_xcd_kernel<<<grid, block, 0, stream>>>(f0, f1, f2, f3, boxes, out);
}